// Round 1
// baseline (79.952 us; speedup 1.0000x reference)
//
#include <hip/hip_runtime.h>

// SpikeFP32LookupExp2: out[pos, p] = table_bits[j(pos), p] where
// j(pos) = sum_k (idx_bits[pos,k] > 0.5) << k.  idx_bits are exact 0.0/1.0,
// so the reference's one-hot einsum reduces to a row gather.
//
// 8 threads cooperate per position: each computes j (5 scalar loads,
// L1-broadcast across the 8 lanes) and writes one float4 -> each 8-lane
// group stores a contiguous 128 B output row (fully coalesced).

__global__ __launch_bounds__(256) void spike_lookup_kernel(
    const float* __restrict__ idx_bits,   // [n_pos * 5]
    const float* __restrict__ table_bits, // [32 * 32]
    float* __restrict__ out,              // [n_pos * 32]
    int n_pos) {
  int gid = blockIdx.x * blockDim.x + threadIdx.x;
  int pos = gid >> 3;       // position handled by this 8-lane group
  int lane8 = gid & 7;      // which float4 of the 32-float row
  if (pos >= n_pos) return;

  const float* b = idx_bits + (long)pos * 5;
  unsigned j = 0;
#pragma unroll
  for (int k = 0; k < 5; ++k) {
    j |= (b[k] > 0.5f) ? (1u << k) : 0u;
  }

  // Gather 16 B of row j from the 4 KB table (L1-resident).
  const float4 row =
      *reinterpret_cast<const float4*>(table_bits + (j << 5) + (lane8 << 2));

  *reinterpret_cast<float4*>(out + ((long)pos << 5) + (lane8 << 2)) = row;
}

extern "C" void kernel_launch(void* const* d_in, const int* in_sizes, int n_in,
                              void* d_out, int out_size, void* d_ws, size_t ws_size,
                              hipStream_t stream) {
  const float* idx_bits = (const float*)d_in[0];     // (1024, 2048, 5) f32
  const float* table_bits = (const float*)d_in[1];   // (32, 32) f32
  float* out = (float*)d_out;                        // (1024, 2048, 32) f32

  const int n_pos = in_sizes[0] / 5;                 // 2,097,152
  const long n_threads = (long)n_pos * 8;            // one float4 per thread
  const int block = 256;
  const int grid = (int)((n_threads + block - 1) / block);  // 65,536

  spike_lookup_kernel<<<grid, block, 0, stream>>>(idx_bits, table_bits, out, n_pos);
}

// Round 3
// 51.609 us; speedup vs baseline: 1.5492x; 1.5492x over previous
//
#include <hip/hip_runtime.h>

// SpikeFP32LookupExp2: out[pos, :] = table_bits[j(pos), :] where
// j(pos) = sum_k (idx_bits[pos,k] > 0.5) << k.  Pure row-gather, memory-bound
// (~308 MB traffic, write-dominated; fill-kernel ceiling on this box ~7 TB/s).
//
// Structure (round 3 = round 2 with compile fix):
//  - 8 lanes per position; each lane stores one float4 of the 128 B row
//    (fully coalesced, 1 KB per wave store instruction).
//  - j via ballot: lanes with lane8<5 load one bit each (single coalesced
//    dword load per wave), j = (ballot >> group_base) & 31.  8x fewer idx
//    load instructions than the naive 5-loads-per-lane version.
//  - Grid-stride loop (16 iterations/thread) with unroll-4 so 4 independent
//    iterations' loads are in flight per wave -> hides HBM latency that a
//    single-shot thread (one dependent chain, 8 waves/SIMD) cannot.
//  - Nontemporal stores via clang ext_vector_type (HIP float4 is a struct
//    and __builtin_nontemporal_store rejects it).

typedef float floatx4 __attribute__((ext_vector_type(4)));

__global__ __launch_bounds__(256) void spike_lookup_kernel(
    const float* __restrict__ idx_bits,   // [n_pos * 5]
    const float* __restrict__ table_bits, // [32 * 32]
    float* __restrict__ out,              // [n_pos * 32]
    long n_pos) {
  const long total4 = n_pos * 8;  // total float4 outputs
  const long nthreads = (long)gridDim.x * blockDim.x;
  const long gid = (long)blockIdx.x * blockDim.x + threadIdx.x;
  const int lane8 = (int)(gid & 7);        // which float4 of the row
  const unsigned shift = threadIdx.x & 56; // group base within the wave

#pragma unroll 4
  for (long g = gid; g < total4; g += nthreads) {
    const long pos = g >> 3;
    float v = 0.0f;
    if (lane8 < 5) v = idx_bits[pos * 5 + lane8];  // one bit per lane
    const unsigned long long m = __ballot(v > 0.5f);
    const unsigned j = (unsigned)((m >> shift) & 31ull);

    const floatx4 row = *reinterpret_cast<const floatx4*>(
        table_bits + (j << 5) + (lane8 << 2));     // 4 KB table, L1-resident

    __builtin_nontemporal_store(row,
                                reinterpret_cast<floatx4*>(out + (g << 2)));
  }
}

extern "C" void kernel_launch(void* const* d_in, const int* in_sizes, int n_in,
                              void* d_out, int out_size, void* d_ws, size_t ws_size,
                              hipStream_t stream) {
  const float* idx_bits = (const float*)d_in[0];    // (1024, 2048, 5) f32
  const float* table_bits = (const float*)d_in[1];  // (32, 32) f32
  float* out = (float*)d_out;                       // (1024, 2048, 32) f32

  const long n_pos = in_sizes[0] / 5;  // 2,097,152
  const int block = 256;
  const int grid = 4096;  // 1,048,576 threads -> 16 float4s per thread

  spike_lookup_kernel<<<grid, block, 0, stream>>>(idx_bits, table_bits, out,
                                                  n_pos);
}